// Round 11
// baseline (634.075 us; speedup 1.0000x reference)
//
#include <hip/hip_runtime.h>
#include <hip/hip_bf16.h>

typedef __attribute__((ext_vector_type(8))) short bfrag8;   // 8 bf16 in 4 VGPRs
typedef __attribute__((ext_vector_type(4))) float f32x4;

#define DIV_UP(a,b) (((a)+(b)-1)/(b))

__device__ __forceinline__ float sigm(float x){ return 1.0f/(1.0f + __expf(-x)); }
__device__ __forceinline__ float fast_tanh(float x){
  float ax = fabsf(x);
  float t = __expf(-2.0f*ax);
  float r = (1.0f - t)/(1.0f + t);
  return copysignf(r, x);
}
__device__ __forceinline__ float bf2f(short s){
  unsigned int u = ((unsigned int)(unsigned short)s) << 16;
  return __uint_as_float(u);
}
__device__ __forceinline__ unsigned short f2bf_bits(float x){
  __hip_bfloat16 b = __float2bfloat16(x);
  return *reinterpret_cast<unsigned short*>(&b);
}

#define GLOAD_LDS16(g, l) \
  __builtin_amdgcn_global_load_lds((const __attribute__((address_space(1))) void*)(g), \
                                   (__attribute__((address_space(3))) void*)(l), 16, 0, 0)

// ---------------- weight / embedding conversion ----------------
__global__ void conv_emb4(const float* __restrict__ e, __hip_bfloat16* __restrict__ o){
  int idx = blockIdx.x*256 + threadIdx.x;           // chunk id over [32000][80]
  if (idx >= 32000*80) return;
  int v = idx / 80, c = idx - v*80;
  ushort4 r;
  if (c < 75) {
    float4 f = *(const float4*)(e + (size_t)v*300 + c*4);
    r.x = f2bf_bits(f.x); r.y = f2bf_bits(f.y); r.z = f2bf_bits(f.z); r.w = f2bf_bits(f.w);
  } else { r.x = r.y = r.z = r.w = 0; }
  *(ushort4*)((unsigned short*)o + (size_t)v*320 + c*4) = r;
}
// WiouT interleaved: n = (e>>4)*48 + gate*16 + (e&15), gate in {i,o,u}; [768][320]
__global__ void conv_wiou_i(const float* __restrict__ Wf, __hip_bfloat16* __restrict__ o){
  int idx = blockIdx.x*256 + threadIdx.x;
  if (idx >= 768*320) return;
  int n = idx / 320, k = idx - n*320;
  int eg = n / 48, rem = n - eg*48, gate = rem >> 4, es = rem & 15;
  int e = eg*16 + es;
  o[idx] = __float2bfloat16(k < 300 ? Wf[(size_t)k*768 + gate*256 + e] : 0.0f);
}
// UcatT interleaved: n = (e>>4)*80 + gate*16 + (e&15), gate in {i,o,u,f0,f1}; [1280][512]
__global__ void conv_ucat_i(const float* __restrict__ Ui, const float* __restrict__ Uf,
                            __hip_bfloat16* __restrict__ o){
  int idx = blockIdx.x*256 + threadIdx.x;
  if (idx >= 1280*512) return;
  int n = idx >> 9, k = idx & 511;
  int eg = n / 80, rem = n - eg*80, gate = rem >> 4, es = rem & 15;
  int e = eg*16 + es;
  float v = (gate < 3) ? Ui[(size_t)k*768 + gate*256 + e]
                       : Uf[(size_t)k*512 + (gate-3)*256 + e];
  o[idx] = __float2bfloat16(v);
}

// ---------------- fused GEMM + gates: reg-A + 4-buf LDS-B, 1 barrier/step ----------------
// Round-11 structure. Round-10 accounting: per block-step wall ~1458 cyc matched the
// LDS-DMA staging volume (18 KB @ ~12 B/cyc/CU), not MFMA (26%) or LDS-read (40%).
// => A (8 KB/step, per-lane fragment data, no cross-wave sharing) moves to DIRECT
// register loads: each lane loads its 4x16B A-fragments for step ks+1 at the END of
// step ks (full-step latency cover, decoupled from barriers). B (shared by 4 waves)
// stays LDS-staged via global_load_lds in 4 rotating buffers, ONE barrier per step:
//   wait vmcnt(nb+4)  [drains own BST(ks); keeps BST(ks+1)+ALD(ks) in flight]
//   barrier           [B(ks) visible to all; buf (ks+2)&3's readers (step ks-2) done]
//   BST(ks+2) -> buf (ks+2)&3 ; ds_read bfv from buf ks&3 ; 4xNG MFMA ; ALD(ks+1)
// Compiler auto-inserts the precise vmcnt for the af-register RAW (it tracks its own
// loads); manual waits only cover the B DMA. Last iter: vmcnt(4). nb wave-uniform.
// XCD co-location swizzle kept (FETCH 277->117 MB). __launch_bounds__(256,3); LDS
// 4*BUFB = 40 KB (NG=5) -> still 3 blocks/CU (round-9 lesson: never drop below 3).
template<int NG, bool G2>
__global__ __launch_bounds__(256, 3) void gemm_fused(
    const char* __restrict__ Ab,      // A bytes (direct) | h_voc bytes (G2: gather pairs)
    const int*  __restrict__ wid,     // G2 only: leaf wordids (children 2m, 2m+1)
    const char* __restrict__ Btb,     // interleaved [N][K] bf16
    int M, int K, int Kb,             // Kb = A row stride bytes (direct mode)
    const float* __restrict__ b_iou,  // [768] original layout
    const float* __restrict__ b_f,    // [512] (NG=5)
    const float* __restrict__ cprev,  // fp32 children c (table when G2)
    __hip_bfloat16* __restrict__ Hout, float* __restrict__ Cout)
{
  constexpr int GW   = NG*16;         // wave col width (one e-group, NG gates)
  constexpr int BN   = 2*GW;          // block cols
  constexpr int BCH  = BN*4;          // B chunks (16B) per K-step
  constexpr int BUFB = BN*64;         // bytes per B buffer
  __shared__ __align__(16) char lds[4*BUFB];

  const int lx = blockIdx.y & 7;
  const int ly = ((blockIdx.y >> 3) << 3) | (blockIdx.x & 7);
  const int row0 = ly*128;
  if (row0 >= M) return;              // padded grid.y tail (uniform per block)

  const int t = threadIdx.x, lane = t & 63, w = t >> 6;
  const int wr = w >> 1, wc = w & 1;
  const int frow = lane & 15, g = lane >> 4;
  const size_t colbase = (size_t)lx * BN;
  const size_t Kbyt = (size_t)K*2;

  // ---- B staging descriptors (de-swizzled chunk -> (row,q)); per-thread count nb ----
  const char* bbase[3];
  const int nb = (t < 128) ? ((NG==5) ? 3 : 2) : ((NG==5) ? 2 : 1);
  #pragma unroll
  for (int i = 0; i < 3; ++i) {
    int cb = t + i*256;
    if (cb < BCH) {
      int rp = cb >> 3, lc = (cb & 7) ^ (rp & 7);
      int r = rp*2 + (lc >> 2), q = lc & 3;
      bbase[i] = Btb + (colbase + r)*Kbyt + q*16;
    } else bbase[i] = Btb;
  }

  // ---- per-lane A fragment offsets (32-bit; uniform kb0 added per step) ----
  int aoff0[4], aoff1[4];
  #pragma unroll
  for (int mi = 0; mi < 4; ++mi) {
    int row = row0 + wr*64 + mi*16 + frow;
    row = row < M ? row : M-1;
    if constexpr (G2) {
      aoff0[mi] = wid[2*row]*512 + g*16;
      aoff1[mi] = wid[2*row+1]*512 + g*16 - 512;   // so Ab + kb0 + aoff1 is right for kb0>=512
    } else {
      aoff0[mi] = row*Kb + g*16;
      aoff1[mi] = aoff0[mi];
    }
  }

  bfrag8 af[4];
  auto ALD = [&](int kb0){
    #pragma unroll
    for (int mi = 0; mi < 4; ++mi) {
      int off = (G2 && kb0 >= 512) ? aoff1[mi] : aoff0[mi];
      af[mi] = *(const bfrag8*)(Ab + (size_t)(kb0 + off));
    }
  };
  auto BST = [&](int buf, int ks2){
    const int kb0 = ks2*64;
    char* lb = lds + buf*BUFB;
    #pragma unroll
    for (int i = 0; i < 3; ++i)
      if (i < nb) GLOAD_LDS16(bbase[i] + kb0, lb + (t + i*256)*16);
  };

  // swizzled B read offsets (lane-constant across gi)
  const int fr2 = frow >> 1;
  const int pc  = (((frow & 1)*4 + g) ^ (fr2 & 7));
  const int boff = wc*(GW*64) + fr2*128 + pc*16;

  f32x4 acc[4][NG] = {};
  const int nsteps = K >> 5;

  // prologue: outstanding = BST(0)[nb], ALD(0)[4], BST(1)[nb]
  BST(0, 0);
  ALD(0);
  BST(1, 1);

  for (int ks = 0; ks < nsteps; ++ks) {
    // drain own BST(ks) (and older); keep BST(ks+1)+ALD(ks) in flight
    if (ks + 1 < nsteps) {
      if constexpr (NG == 5) {
        if (w < 2) asm volatile("s_waitcnt vmcnt(7)" ::: "memory");
        else       asm volatile("s_waitcnt vmcnt(6)" ::: "memory");
      } else {
        if (w < 2) asm volatile("s_waitcnt vmcnt(6)" ::: "memory");
        else       asm volatile("s_waitcnt vmcnt(5)" ::: "memory");
      }
    } else {
      asm volatile("s_waitcnt vmcnt(4)" ::: "memory");   // only ALD(ks) may stay
    }
    __builtin_amdgcn_s_barrier();          // B(ks) visible to all waves
    asm volatile("" ::: "memory");

    if (ks + 2 < nsteps) BST((ks + 2) & 3, ks + 2);

    const char* lb = lds + (ks & 3)*BUFB;
    bfrag8 bfv[NG];
    #pragma unroll
    for (int gi = 0; gi < NG; ++gi) bfv[gi] = *(const bfrag8*)(lb + boff + gi*1024);
    #pragma unroll
    for (int mi = 0; mi < 4; ++mi)
      #pragma unroll
      for (int gi = 0; gi < NG; ++gi)
        acc[mi][gi] = __builtin_amdgcn_mfma_f32_16x16x32_bf16(af[mi], bfv[gi], acc[mi][gi], 0, 0, 0);

    // reload A fragments for next step (clamped last iter; full-step latency cover)
    const int kn = (ks + 1 < nsteps) ? ks + 1 : ks;
    ALD(kn*64);
  }

  // ---- fused gate epilogue (C/D layout: col=frow, row=g*4+r) ----
  const int e = lx*32 + wc*16 + frow;
  const float bi = b_iou[e], bo = b_iou[256+e], bu = b_iou[512+e];
  float bf0 = 0.f, bf1 = 0.f;
  if constexpr (NG == 5) { bf0 = b_f[e]; bf1 = b_f[256+e]; }
  #pragma unroll
  for (int mi = 0; mi < 4; ++mi) {
    const int mb = row0 + wr*64 + mi*16 + g*4;
    #pragma unroll
    for (int r = 0; r < 4; ++r) {
      const int m = mb + r;
      if (m < M) {
        float cv = sigm(acc[mi][0][r] + bi) * fast_tanh(acc[mi][2][r] + bu);
        if constexpr (NG == 5) {
          const size_t c0i = G2 ? (size_t)wid[2*m]   : (size_t)(2*m);
          const size_t c1i = G2 ? (size_t)wid[2*m+1] : (size_t)(2*m+1);
          cv += sigm(acc[mi][3][r] + bf0) * cprev[c0i*256 + e]
              + sigm(acc[mi][4][r] + bf1) * cprev[c1i*256 + e];
        }
        Cout[(size_t)m*256 + e] = cv;
        Hout[(size_t)m*256 + e] = __float2bfloat16(sigm(acc[mi][1][r] + bo) * fast_tanh(cv));
      }
    }
  }
}

// ---------------- vectorized output projection ----------------
__global__ void outproj_v(const __hip_bfloat16* __restrict__ h, int M,
                          const float* __restrict__ Wout, const float* __restrict__ bout,
                          float* __restrict__ out){
  const int t = threadIdx.x;
  const int half = t >> 5, l32 = t & 31;
  const int e0 = l32 * 8;
  float wv[8][5];
  #pragma unroll
  for (int j = 0; j < 8; ++j)
    #pragma unroll
    for (int cl = 0; cl < 5; ++cl) wv[j][cl] = Wout[(e0+j)*5 + cl];
  const float b0 = bout[0], b1 = bout[1], b2 = bout[2], b3 = bout[3], b4 = bout[4];
  for (int row = blockIdx.x*8 + half; row < M; row += gridDim.x*8) {
    bfrag8 hv = *(const bfrag8*)((const short*)h + (size_t)row*256 + e0);
    float a0=0,a1=0,a2=0,a3=0,a4=0;
    #pragma unroll
    for (int j = 0; j < 8; ++j) {
      float x = bf2f(hv[j]);
      a0 += x*wv[j][0]; a1 += x*wv[j][1]; a2 += x*wv[j][2]; a3 += x*wv[j][3]; a4 += x*wv[j][4];
    }
    #pragma unroll
    for (int off = 16; off; off >>= 1) {
      a0 += __shfl_down(a0, off); a1 += __shfl_down(a1, off);
      a2 += __shfl_down(a2, off); a3 += __shfl_down(a3, off); a4 += __shfl_down(a4, off);
    }
    if (l32 == 0) {
      float* op = out + (size_t)row*5;
      op[0]=a0+b0; op[1]=a1+b1; op[2]=a2+b2; op[3]=a3+b3; op[4]=a4+b4;
    }
  }
}

// ---------------- leaf output scatter: out[p] = outvoc[wordid[p]] ----------------
__global__ void leaf_scatter(const int* __restrict__ wid, const float* __restrict__ outvoc,
                             float* __restrict__ out){
  int p = blockIdx.x*256 + threadIdx.x;
  if (p >= 131072) return;
  const float* s = outvoc + (size_t)wid[p]*5;
  float* d = out + (size_t)p*5;
  #pragma unroll
  for (int j = 0; j < 5; ++j) d[j] = s[j];
}

extern "C" void kernel_launch(void* const* d_in, const int* in_sizes, int n_in,
                              void* d_out, int out_size, void* d_ws, size_t ws_size,
                              hipStream_t stream) {
  const int* wordid   = (const int*)d_in[0];
  const float* emb    = (const float*)d_in[1];
  const float* W_iou  = (const float*)d_in[2];
  const float* b_Wiou = (const float*)d_in[3];
  const float* U_iou  = (const float*)d_in[4];
  const float* b_Uiou = (const float*)d_in[5];
  const float* U_f    = (const float*)d_in[6];
  const float* b_Uf   = (const float*)d_in[7];
  const float* W_out  = (const float*)d_in[8];
  const float* b_out  = (const float*)d_in[9];
  float* out = (float*)d_out;

  char* p = (char*)d_ws;
  auto take = [&](size_t bytes){ char* r = p; p += (bytes + 255) & ~(size_t)255; return r; };
  __hip_bfloat16* wiouT  = (__hip_bfloat16*)take((size_t)768*320*2);
  __hip_bfloat16* ucatT  = (__hip_bfloat16*)take((size_t)1280*512*2);
  __hip_bfloat16* h_voc  = (__hip_bfloat16*)take((size_t)32000*256*2);   // 16.4 MB
  float*          c_voc  = (float*)take((size_t)32000*256*4);            // 32.8 MB
  float*          outvoc = (float*)take((size_t)32000*5*4);
  __hip_bfloat16* hAll   = (__hip_bfloat16*)take((size_t)131008*256*2);  // 67.1 MB (lvls 1-11 packed)
  float*          cA     = (float*)take((size_t)65536*256*4);            // 67.1 MB
  float*          cB     = (float*)take((size_t)32768*256*4);            // 33.6 MB
  // embbf aliases cA: dead before first cA write (lvl-1 gates)
  __hip_bfloat16* embbf  = (__hip_bfloat16*)cA;                          // 20.5 MB

  auto ceil8 = [](int y){ return (y + 7) & ~7; };

  conv_emb4  <<<DIV_UP(32000*80, 256),256,0,stream>>>(emb, embbf);
  conv_wiou_i<<<DIV_UP(768*320,  256),256,0,stream>>>(W_iou, wiouT);
  conv_ucat_i<<<DIV_UP(1280*512, 256),256,0,stream>>>(U_iou, U_f, ucatT);

  // ---- vocab precompute: h_voc/c_voc = leaf-gates(emb @ W_iou + b); outvoc = h_voc @ W_out + b ----
  gemm_fused<3,false><<<dim3(8,ceil8(250)),256,0,stream>>>(
      (const char*)embbf, nullptr, (const char*)wiouT, 32000, 320, 640,
      b_Wiou, nullptr, nullptr, h_voc, c_voc);
  outproj_v<<<1024,256,0,stream>>>(h_voc, 32000, W_out, b_out, outvoc);
  leaf_scatter<<<DIV_UP(131072,256),256,0,stream>>>(wordid, outvoc, out);

  // ---- level 1: gather children straight from vocab tables; h -> hAll[0:65536) ----
  gemm_fused<5,true><<<dim3(8,512),256,0,stream>>>(
      (const char*)h_voc, wordid, (const char*)ucatT, 65536, 512, 0,
      b_Uiou, b_Uf, c_voc, hAll, cA);

  // ---- levels 2..11: A reads prev level's packed h region; h appended into hAll ----
  const __hip_bfloat16* hp = hAll; const float* cp = cA;
  size_t hoff = 65536;
  int Mlvl = 65536;
  for (int lvl = 2; lvl <= 11; ++lvl) {
    Mlvl >>= 1;
    float* cn = (lvl & 1) ? cA : cB;    // lvl1 wrote cA; lvl2 reads cA writes cB; alternate
    gemm_fused<5,false><<<dim3(8,ceil8(DIV_UP(Mlvl,128))),256,0,stream>>>(
        (const char*)hp, nullptr, (const char*)ucatT, Mlvl, 512, 1024,
        b_Uiou, b_Uf, cp, hAll + hoff*256, cn);
    hp = hAll + hoff*256; cp = cn; hoff += Mlvl;
  }

  // ---- single deferred output projection over all internal nodes (131008 rows) ----
  outproj_v<<<2048,256,0,stream>>>(hAll, 131008, W_out, b_out, out + (size_t)131072*5);
}

// Round 12
// 473.845 us; speedup vs baseline: 1.3381x; 1.3381x over previous
//
#include <hip/hip_runtime.h>
#include <hip/hip_bf16.h>

typedef __attribute__((ext_vector_type(8))) short bfrag8;   // 8 bf16 in 4 VGPRs
typedef __attribute__((ext_vector_type(4))) float f32x4;

#define DIV_UP(a,b) (((a)+(b)-1)/(b))

__device__ __forceinline__ float sigm(float x){ return 1.0f/(1.0f + __expf(-x)); }
__device__ __forceinline__ float fast_tanh(float x){
  float ax = fabsf(x);
  float t = __expf(-2.0f*ax);
  float r = (1.0f - t)/(1.0f + t);
  return copysignf(r, x);
}
__device__ __forceinline__ float bf2f(short s){
  unsigned int u = ((unsigned int)(unsigned short)s) << 16;
  return __uint_as_float(u);
}
__device__ __forceinline__ unsigned short f2bf_bits(float x){
  __hip_bfloat16 b = __float2bfloat16(x);
  return *reinterpret_cast<unsigned short*>(&b);
}

#define GLOAD_LDS16(g, l) \
  __builtin_amdgcn_global_load_lds((const __attribute__((address_space(1))) void*)(g), \
                                   (__attribute__((address_space(3))) void*)(l), 16, 0, 0)

// ---------------- merged weight / embedding conversion (1 launch) ----------------
// range 0: emb [32000][320] padded, float4->4x bf16 per thread (2,560,000 chunks)
// range 1: WiouT interleaved n=(e>>4)*48+gate*16+(e&15), [768][320]   (245,760 elems)
// range 2: UcatT interleaved n=(e>>4)*80+gate*16+(e&15), [1280][512]  (655,360 elems)
__global__ void conv_all(const float* __restrict__ emb, const float* __restrict__ Wf,
                         const float* __restrict__ Ui, const float* __restrict__ Uf,
                         __hip_bfloat16* __restrict__ oemb, __hip_bfloat16* __restrict__ owiou,
                         __hip_bfloat16* __restrict__ oucat){
  int idx = blockIdx.x*256 + threadIdx.x;
  if (idx < 32000*80) {
    int v = idx / 80, c = idx - v*80;
    ushort4 r;
    if (c < 75) {
      float4 f = *(const float4*)(emb + (size_t)v*300 + c*4);
      r.x = f2bf_bits(f.x); r.y = f2bf_bits(f.y); r.z = f2bf_bits(f.z); r.w = f2bf_bits(f.w);
    } else { r.x = r.y = r.z = r.w = 0; }
    *(ushort4*)((unsigned short*)oemb + (size_t)v*320 + c*4) = r;
    return;
  }
  idx -= 32000*80;
  if (idx < 768*320) {
    int n = idx / 320, k = idx - n*320;
    int eg = n / 48, rem = n - eg*48, gate = rem >> 4, es = rem & 15;
    int e = eg*16 + es;
    owiou[(size_t)n*320 + k] = __float2bfloat16(k < 300 ? Wf[(size_t)k*768 + gate*256 + e] : 0.0f);
    return;
  }
  idx -= 768*320;
  if (idx < 1280*512) {
    int n = idx >> 9, k = idx & 511;
    int eg = n / 80, rem = n - eg*80, gate = rem >> 4, es = rem & 15;
    int e = eg*16 + es;
    float v = (gate < 3) ? Ui[(size_t)k*768 + gate*256 + e]
                         : Uf[(size_t)k*512 + (gate-3)*256 + e];
    oucat[(size_t)n*512 + k] = __float2bfloat16(v);
  }
}

// ---------------- fused GEMM + gates, 2-phase double-buffered pipeline (round-8/10 best) ----
// Local optimum of this template (rounds 5-11 bracket it): 2-buffer LDS (36.9 KB, 3 blk/CU),
// wave-exact counted vmcnt, 2 barriers/step, (256,3), XCD co-location swizzle.
//  - (256,2)/(256,4): tie / 530 MB spill (r4,r5)     - 4-deep 1-barrier: -18% (r9, occ loss)
//  - reg-A per-lane loads: -30% (r11, 2x A VMEM)     - L-1 vmcnt miscount: -4% (r5-7)
// XCD swizzle: hardware XCD = (bx+8*by)%8 = bx; lx=by&7, ly=(by>>3)*8+bx co-locates the 8
// col-blocks of a row-block on one XCD (FETCH 277->117 MB). grid.y multiple of 8; tail
// blocks exit uniformly before any barrier.
template<int NG, bool G2>
__global__ __launch_bounds__(256, 3) void gemm_fused(
    const char* __restrict__ Ab,      // A bytes (direct) | h_voc bytes (G2: gather pairs)
    const int*  __restrict__ wid,     // G2 only: leaf wordids (children 2m, 2m+1)
    const char* __restrict__ Btb,     // interleaved [N][K] bf16
    int M, int K, int Kb,             // Kb = A row stride bytes (direct mode)
    const float* __restrict__ b_iou,  // [768] original layout
    const float* __restrict__ b_f,    // [512] (NG=5)
    const float* __restrict__ cprev,  // fp32 children c (table when G2)
    __hip_bfloat16* __restrict__ Hout, float* __restrict__ Cout)
{
  constexpr int GW  = NG*16;          // wave col width (one e-group, NG gates)
  constexpr int BN  = 2*GW;           // block cols
  constexpr int BCH = BN*4;           // B chunks (16B) per K-step
  constexpr int BUF = 8192 + BN*64;   // bytes per (A,B) buffer pair
  __shared__ __align__(16) char lds[2*BUF];

  const int lx = blockIdx.y & 7;
  const int ly = ((blockIdx.y >> 3) << 3) | (blockIdx.x & 7);
  const int row0 = ly*128;
  if (row0 >= M) return;              // padded grid.y tail (uniform per block)

  const int t = threadIdx.x, lane = t & 63, w = t >> 6;
  const int wr = w >> 1, wc = w & 1;
  const int frow = lane & 15, g = lane >> 4;
  const size_t colbase = (size_t)lx * BN;
  const size_t Kbyt = (size_t)K*2;

  // ---- ks-invariant staging descriptors (de-swizzled chunk -> (row,q)) ----
  const char* abase0[2]; const char* abase1[2];
  #pragma unroll
  for (int i = 0; i < 2; ++i) {
    int c = t + i*256;
    int rp = c >> 3, lc = (c & 7) ^ (rp & 7);
    int r = rp*2 + (lc >> 2), q = lc & 3;
    int row = row0 + r; row = row < M ? row : M-1;
    if constexpr (G2) {
      abase0[i] = Ab + (size_t)wid[2*row]  *512 + q*16;
      abase1[i] = Ab + (size_t)wid[2*row+1]*512 + q*16 - 512;
    } else {
      abase0[i] = Ab + (size_t)row*Kb + q*16;
      abase1[i] = abase0[i];
    }
  }
  const char* bbase[3];
  const int nb = (t < 128) ? ((NG==5) ? 3 : 2) : ((NG==5) ? 2 : 1);
  #pragma unroll
  for (int i = 0; i < 3; ++i) {
    int cb = t + i*256;
    if (cb < BCH) {
      int rp = cb >> 3, lc = (cb & 7) ^ (rp & 7);
      int r = rp*2 + (lc >> 2), q = lc & 3;
      bbase[i] = Btb + (colbase + r)*Kbyt + q*16;
    } else bbase[i] = Btb;
  }

  auto STAGE = [&](int b, int ks){
    const int kb0 = ks*64;
    char* la = lds + b*BUF;
    char* lb = la + 8192;
    #pragma unroll
    for (int i = 0; i < 2; ++i) {
      const char* s = (G2 && kb0 >= 512) ? abase1[i] + kb0 : abase0[i] + kb0;
      GLOAD_LDS16(s, la + (t + i*256)*16);
    }
    #pragma unroll
    for (int i = 0; i < 3; ++i)
      if (i < nb) GLOAD_LDS16(bbase[i] + kb0, lb + (t + i*256)*16);
  };

  // swizzled read offsets (lane-constant across mi/gi)
  const int fr2 = frow >> 1;
  const int pc  = (((frow & 1)*4 + g) ^ (fr2 & 7));
  const int aoff = wr*4096 + fr2*128 + pc*16;
  const int boff = wc*(GW*64) + fr2*128 + pc*16;

  f32x4 acc[4][NG] = {};
  const int nsteps = K >> 5;

  STAGE(0, 0);
  for (int ks = 0; ks < nsteps; ++ks) {
    const int b = ks & 1;
    if (ks + 1 < nsteps) {
      STAGE(b ^ 1, ks + 1);
      // wave-exact counted wait: outstanding <= own stage-load count L
      if constexpr (NG == 5) {
        if (w < 2) asm volatile("s_waitcnt vmcnt(5)" ::: "memory");
        else       asm volatile("s_waitcnt vmcnt(4)" ::: "memory");
      } else {
        if (w < 2) asm volatile("s_waitcnt vmcnt(4)" ::: "memory");
        else       asm volatile("s_waitcnt vmcnt(3)" ::: "memory");
      }
    } else {
      asm volatile("s_waitcnt vmcnt(0)" ::: "memory");
    }
    __builtin_amdgcn_s_barrier();          // buf[b] ready for all waves
    asm volatile("" ::: "memory");

    const char* la = lds + b*BUF;
    const char* lb = la + 8192;
    bfrag8 af[4], bfv[NG];
    #pragma unroll
    for (int mi = 0; mi < 4; ++mi) af[mi] = *(const bfrag8*)(la + aoff + mi*1024);
    #pragma unroll
    for (int gi = 0; gi < NG; ++gi) bfv[gi] = *(const bfrag8*)(lb + boff + gi*1024);
    #pragma unroll
    for (int mi = 0; mi < 4; ++mi)
      #pragma unroll
      for (int gi = 0; gi < NG; ++gi)
        acc[mi][gi] = __builtin_amdgcn_mfma_f32_16x16x32_bf16(af[mi], bfv[gi], acc[mi][gi], 0, 0, 0);

    asm volatile("" ::: "memory");
    __builtin_amdgcn_s_barrier();          // all waves done reading buf[b]
  }

  // ---- fused gate epilogue (C/D layout: col=frow, row=g*4+r) ----
  const int e = lx*32 + wc*16 + frow;
  const float bi = b_iou[e], bo = b_iou[256+e], bu = b_iou[512+e];
  float bf0 = 0.f, bf1 = 0.f;
  if constexpr (NG == 5) { bf0 = b_f[e]; bf1 = b_f[256+e]; }
  #pragma unroll
  for (int mi = 0; mi < 4; ++mi) {
    const int mb = row0 + wr*64 + mi*16 + g*4;
    #pragma unroll
    for (int r = 0; r < 4; ++r) {
      const int m = mb + r;
      if (m < M) {
        float cv = sigm(acc[mi][0][r] + bi) * fast_tanh(acc[mi][2][r] + bu);
        if constexpr (NG == 5) {
          const size_t c0i = G2 ? (size_t)wid[2*m]   : (size_t)(2*m);
          const size_t c1i = G2 ? (size_t)wid[2*m+1] : (size_t)(2*m+1);
          cv += sigm(acc[mi][3][r] + bf0) * cprev[c0i*256 + e]
              + sigm(acc[mi][4][r] + bf1) * cprev[c1i*256 + e];
        }
        Cout[(size_t)m*256 + e] = cv;
        Hout[(size_t)m*256 + e] = __float2bfloat16(sigm(acc[mi][1][r] + bo) * fast_tanh(cv));
      }
    }
  }
}

// ---------------- vectorized output projection ----------------
__global__ void outproj_v(const __hip_bfloat16* __restrict__ h, int M,
                          const float* __restrict__ Wout, const float* __restrict__ bout,
                          float* __restrict__ out){
  const int t = threadIdx.x;
  const int half = t >> 5, l32 = t & 31;
  const int e0 = l32 * 8;
  float wv[8][5];
  #pragma unroll
  for (int j = 0; j < 8; ++j)
    #pragma unroll
    for (int cl = 0; cl < 5; ++cl) wv[j][cl] = Wout[(e0+j)*5 + cl];
  const float b0 = bout[0], b1 = bout[1], b2 = bout[2], b3 = bout[3], b4 = bout[4];
  for (int row = blockIdx.x*8 + half; row < M; row += gridDim.x*8) {
    bfrag8 hv = *(const bfrag8*)((const short*)h + (size_t)row*256 + e0);
    float a0=0,a1=0,a2=0,a3=0,a4=0;
    #pragma unroll
    for (int j = 0; j < 8; ++j) {
      float x = bf2f(hv[j]);
      a0 += x*wv[j][0]; a1 += x*wv[j][1]; a2 += x*wv[j][2]; a3 += x*wv[j][3]; a4 += x*wv[j][4];
    }
    #pragma unroll
    for (int off = 16; off; off >>= 1) {
      a0 += __shfl_down(a0, off); a1 += __shfl_down(a1, off);
      a2 += __shfl_down(a2, off); a3 += __shfl_down(a3, off); a4 += __shfl_down(a4, off);
    }
    if (l32 == 0) {
      float* op = out + (size_t)row*5;
      op[0]=a0+b0; op[1]=a1+b1; op[2]=a2+b2; op[3]=a3+b3; op[4]=a4+b4;
    }
  }
}

// ---------------- leaf output scatter: out[p] = outvoc[wordid[p]] ----------------
__global__ void leaf_scatter(const int* __restrict__ wid, const float* __restrict__ outvoc,
                             float* __restrict__ out){
  int p = blockIdx.x*256 + threadIdx.x;
  if (p >= 131072) return;
  const float* s = outvoc + (size_t)wid[p]*5;
  float* d = out + (size_t)p*5;
  #pragma unroll
  for (int j = 0; j < 5; ++j) d[j] = s[j];
}

extern "C" void kernel_launch(void* const* d_in, const int* in_sizes, int n_in,
                              void* d_out, int out_size, void* d_ws, size_t ws_size,
                              hipStream_t stream) {
  const int* wordid   = (const int*)d_in[0];
  const float* emb    = (const float*)d_in[1];
  const float* W_iou  = (const float*)d_in[2];
  const float* b_Wiou = (const float*)d_in[3];
  const float* U_iou  = (const float*)d_in[4];
  const float* b_Uiou = (const float*)d_in[5];
  const float* U_f    = (const float*)d_in[6];
  const float* b_Uf   = (const float*)d_in[7];
  const float* W_out  = (const float*)d_in[8];
  const float* b_out  = (const float*)d_in[9];
  float* out = (float*)d_out;

  char* p = (char*)d_ws;
  auto take = [&](size_t bytes){ char* r = p; p += (bytes + 255) & ~(size_t)255; return r; };
  __hip_bfloat16* wiouT  = (__hip_bfloat16*)take((size_t)768*320*2);
  __hip_bfloat16* ucatT  = (__hip_bfloat16*)take((size_t)1280*512*2);
  __hip_bfloat16* h_voc  = (__hip_bfloat16*)take((size_t)32000*256*2);   // 16.4 MB
  float*          c_voc  = (float*)take((size_t)32000*256*4);            // 32.8 MB
  float*          outvoc = (float*)take((size_t)32000*5*4);
  __hip_bfloat16* hAll   = (__hip_bfloat16*)take((size_t)131008*256*2);  // 67.1 MB (lvls 1-11 packed)
  float*          cA     = (float*)take((size_t)65536*256*4);            // 67.1 MB
  float*          cB     = (float*)take((size_t)32768*256*4);            // 33.6 MB
  // embbf aliases cA: dead before first cA write (lvl-1 gates)
  __hip_bfloat16* embbf  = (__hip_bfloat16*)cA;                          // 20.5 MB

  auto ceil8 = [](int y){ return (y + 7) & ~7; };

  // ---- single merged conversion launch (emb + WiouT + UcatT) ----
  const int convN = 32000*80 + 768*320 + 1280*512;
  conv_all<<<DIV_UP(convN,256),256,0,stream>>>(emb, W_iou, U_iou, U_f, embbf, wiouT, ucatT);

  // ---- vocab precompute: h_voc/c_voc = leaf-gates(emb @ W_iou + b); outvoc = h_voc @ W_out + b ----
  gemm_fused<3,false><<<dim3(8,ceil8(250)),256,0,stream>>>(
      (const char*)embbf, nullptr, (const char*)wiouT, 32000, 320, 640,
      b_Wiou, nullptr, nullptr, h_voc, c_voc);
  outproj_v<<<1024,256,0,stream>>>(h_voc, 32000, W_out, b_out, outvoc);
  leaf_scatter<<<DIV_UP(131072,256),256,0,stream>>>(wordid, outvoc, out);

  // ---- level 1: gather children straight from vocab tables; h -> hAll[0:65536) ----
  gemm_fused<5,true><<<dim3(8,512),256,0,stream>>>(
      (const char*)h_voc, wordid, (const char*)ucatT, 65536, 512, 0,
      b_Uiou, b_Uf, c_voc, hAll, cA);

  // ---- levels 2..11: A reads prev level's packed h region; h appended into hAll ----
  const __hip_bfloat16* hp = hAll; const float* cp = cA;
  size_t hoff = 65536;
  int Mlvl = 65536;
  for (int lvl = 2; lvl <= 11; ++lvl) {
    Mlvl >>= 1;
    float* cn = (lvl & 1) ? cA : cB;    // lvl1 wrote cA; lvl2 reads cA writes cB; alternate
    gemm_fused<5,false><<<dim3(8,ceil8(DIV_UP(Mlvl,128))),256,0,stream>>>(
        (const char*)hp, nullptr, (const char*)ucatT, Mlvl, 512, 1024,
        b_Uiou, b_Uf, cp, hAll + hoff*256, cn);
    hp = hAll + hoff*256; cp = cn; hoff += Mlvl;
  }

  // ---- single deferred output projection over all internal nodes (131008 rows) ----
  outproj_v<<<2048,256,0,stream>>>(hAll, 131008, W_out, b_out, out + (size_t)131072*5);
}